// Round 2
// 253.918 us; speedup vs baseline: 1.0115x; 1.0115x over previous
//
#include <hip/hip_runtime.h>
#include <cmath>

#define LBINS 401
#define LL 160801
#define MIN_SEP 2
#define PSTRIDE 405      // per-partial floats: 401 bins + HA,HC,SWm,SMm
#define UNR 8

// accum column layout (floats)
#define ACC_HANY  401
#define ACC_HCONV 402
#define ACC_SWM   403
#define ACC_SMM   404

// ---------------------------------------------------------------------------
// main: skewed-torus diagonal walk (lane owns diagonal k; j=(i+k) mod 401).
// Masks staged as packed BITS instead of float4s:
//   col byte: b0=any_j, b1=rev_j, b2=comp_j
//   row byte: b0=any_i, b1=fwd_i, b2=!comp_i   ((row^col)&4 != 0 <=> same comp)
// Hot loop: 1 global dword + 1 ds_read_u8 per element + 1 ds_read_b64 per
// 8 elements (rows, loop 8-aligned) -- ~7x less LDS issue than 2x b128.
// Conditional adds via sign-extended bit masks & float bits: adds the exact
// same rc / c / 0.0f values as the float4-mask version (bit-identical sums).
// y==0 blocks also compute the per-batch closed-form counts (fused prep)
// from the staged bits and write exact int partials. Block (0,0) zeroes the
// reduce-finish counter (stream order guarantees it lands before reduce).
// ---------------------------------------------------------------------------
__global__ __launch_bounds__(256)
void main_kernel(const float* __restrict__ cm,
                 const float* __restrict__ logits,
                 const int* __restrict__ ctcf,
                 float* __restrict__ parts,
                 int* __restrict__ partsI,
                 int* __restrict__ cnt) {
    int b      = blockIdx.x;
    int B      = gridDim.x;
    int ihalf  = blockIdx.y & 1;
    int kgroup = blockIdx.y >> 1;
    int u      = threadIdx.x;
    int k      = kgroup * 256 + u;
    bool active = (k < LBINS);

    __shared__ unsigned char colx8[LBINS];
    __shared__ __align__(8) unsigned char row8[LBINS + 7];
    __shared__ float lb[LBINS];
    __shared__ float sred[4][4];
    __shared__ int   ired[4][4];

    const int*   ct = ctcf   + (size_t)b * LBINS;
    const float* lg = logits + (size_t)b * LBINS * 2;
    for (int t = u; t < LBINS; t += 256) {
        int o = ct[t];
        unsigned any = (o != 0)  ? 1u : 0u;
        unsigned rev = (o == -1) ? 1u : 0u;
        unsigned fwd = (o == 1)  ? 1u : 0u;
        unsigned cj  = (lg[2 * t + 1] > lg[2 * t]) ? 1u : 0u;
        colx8[t] = (unsigned char)(any | (rev << 1) | (cj << 2));
        row8[t]  = (unsigned char)(any | (fwd << 1) | ((1u - cj) << 2));
        lb[t] = 0.f;
    }
    if (u < 7) row8[LBINS + u] = 0;
    if (b == 0 && blockIdx.y == 0 && u == 0)
        __hip_atomic_store(cnt, 0, __ATOMIC_RELAXED, __HIP_MEMORY_SCOPE_AGENT);
    __syncthreads();

    if (blockIdx.y == 0) {
        // fused prep: all per-batch counts derive from the staged col bits
        int na = 0, nr = 0, n1 = 0, adj = 0;
        for (int t = u; t < LBINS; t += 256) {
            unsigned cb = colx8[t];
            na += (int)(cb & 1u);
            nr += (int)((cb >> 1) & 1u);
            n1 += (int)((cb >> 2) & 1u);
            if (t >= 1) adj += (int)((((cb ^ colx8[t - 1]) >> 2) & 1u) ^ 1u);
        }
        #pragma unroll
        for (int off = 32; off > 0; off >>= 1) {
            na  += __shfl_down(na,  off, 64);
            nr  += __shfl_down(nr,  off, 64);
            n1  += __shfl_down(n1,  off, 64);
            adj += __shfl_down(adj, off, 64);
        }
        int w = u >> 6;
        if ((u & 63) == 0) {
            ired[w][0] = na; ired[w][1] = nr; ired[w][2] = n1; ired[w][3] = adj;
        }
        __syncthreads();
        if (u == 0) {
            int NA = ired[0][0] + ired[1][0] + ired[2][0] + ired[3][0];
            int NR = ired[0][1] + ired[1][1] + ired[2][1] + ired[3][1];
            int N1 = ired[0][2] + ired[1][2] + ired[2][2] + ired[3][2];
            int AD = ired[0][3] + ired[1][3] + ired[2][3] + ired[3][3];
            int NF = NA - NR;
            int N0 = LBINS - N1;
            partsI[b]     = NA * NA - NF * NR;                       // nc per batch
            partsI[B + b] = N0 * N0 + N1 * N1 - LBINS - 2 * AD;      // same per batch
        }
    }

    int i0 = ihalf ? 201 : 0;
    int ie = ihalf ? LBINS : 201;

    const float* cmb = cm + (size_t)b * LL;
    float HA = 0.f, HC = 0.f;
    float SMk = 0.f, SMw = 0.f, SWk = 0.f, SWw = 0.f;

    if (active) {
        auto scalar_step = [&](int ii) {
            int j = ii + k;
            int wrapped = (j >= LBINS);
            int jc = wrapped ? j - LBINS : j;
            float c = cmb[(size_t)ii * LBINS + jc];
            unsigned cbq = colx8[jc];
            unsigned rbq = row8[ii];
            float rc = fmaxf(c, 0.f);
            unsigned bnd = rbq & cbq;
            int m0 = (int)(bnd << 31) >> 31;             // any_i & any_j
            int m1 = (int)(bnd << 30) >> 31;             // fwd_i & rev_j
            int ms = (int)((rbq ^ cbq) << 29) >> 31;     // comp_i == comp_j
            HA += __int_as_float(__float_as_int(rc) & m0);
            HC += __int_as_float(__float_as_int(rc) & m1);
            float cs = __int_as_float(__float_as_int(c) & ms);
            SMw += wrapped ? c   : 0.f;
            SMk += wrapped ? 0.f : c;
            SWw += wrapped ? cs  : 0.f;
            SWk += wrapped ? 0.f : cs;
        };

        int i  = i0;
        int iu = i0 + ((8 - (i0 & 7)) & 7);      // first 8-aligned i
        if (iu > ie) iu = ie;
        for (; i < iu; ++i) scalar_step(i);      // prologue (7 iters for ihalf=1)
        for (; i + UNR <= ie; i += UNR) {
            // 8 row-bit bytes in one aligned ds_read_b64 (i % 8 == 0)
            unsigned long long rwin = *(const unsigned long long*)(row8 + i);
            float    cv[UNR];
            unsigned cb[UNR];
            int      wr[UNR];
            #pragma unroll
            for (int q = 0; q < UNR; ++q) {
                int ii = i + q;
                int j  = ii + k;
                int wrapped = (j >= LBINS);
                int jc = wrapped ? j - LBINS : j;
                cv[q] = cmb[(size_t)ii * LBINS + jc];
                cb[q] = colx8[jc];
                wr[q] = wrapped;
            }
            #pragma unroll
            for (int q = 0; q < UNR; ++q) {
                unsigned rbq = (unsigned)(rwin >> (8 * q)) & 0xffu;
                float c  = cv[q];
                float rc = fmaxf(c, 0.f);
                unsigned bnd = rbq & cb[q];
                int m0 = (int)(bnd << 31) >> 31;
                int m1 = (int)(bnd << 30) >> 31;
                int ms = (int)((rbq ^ cb[q]) << 29) >> 31;
                HA += __int_as_float(__float_as_int(rc) & m0);
                HC += __int_as_float(__float_as_int(rc) & m1);
                float cs = __int_as_float(__float_as_int(c) & ms);
                SMw += wr[q] ? c   : 0.f;
                SMk += wr[q] ? 0.f : c;
                SWw += wr[q] ? cs  : 0.f;
                SWk += wr[q] ? 0.f : cs;
            }
        }
        for (; i < ie; ++i) scalar_step(i);      // tail
    }

    // per-lane epilogue: bins via register sums (two per lane)
    float SWm = 0.f, SMm = 0.f;
    if (active) {
        int dw = LBINS - k;               // d of wrapped part (k>0)
        atomicAdd(&lb[k], SMk);
        if (k > 0) atomicAdd(&lb[dw], SMw);
        float mk = (k  >= MIN_SEP) ? 1.f : 0.f;
        float mw = (dw >= MIN_SEP) ? 1.f : 0.f;
        SWm = SWk * mk + SWw * mw;
        SMm = SMk * mk + SMw * mw;
    }

    #pragma unroll
    for (int off = 32; off > 0; off >>= 1) {
        HA  += __shfl_down(HA,  off, 64);
        HC  += __shfl_down(HC,  off, 64);
        SWm += __shfl_down(SWm, off, 64);
        SMm += __shfl_down(SMm, off, 64);
    }
    int w = u >> 6;
    if ((u & 63) == 0) {
        sred[w][0] = HA; sred[w][1] = HC; sred[w][2] = SWm; sred[w][3] = SMm;
    }
    __syncthreads();

    float* pout = parts + (size_t)(blockIdx.y * gridDim.x + blockIdx.x) * PSTRIDE;
    for (int t = u; t < LBINS; t += 256) pout[t] = lb[t];
    if (u == 0) {
        float a = 0.f, c2 = 0.f, s = 0.f, m = 0.f;
        #pragma unroll
        for (int q = 0; q < 4; ++q) {
            a += sred[q][0]; c2 += sred[q][1]; s += sred[q][2]; m += sred[q][3];
        }
        pout[ACC_HANY] = a; pout[ACC_HCONV] = c2;
        pout[ACC_SWM]  = s; pout[ACC_SMM]   = m;
    }
}

// ---------------------------------------------------------------------------
// reduce + fused final: block s sums column s over all partials (float cols
// 0..404; int cols 405/406 sum the exact per-batch counts). The last block
// to finish (agent-scope counter) runs the final scalar math. 256-thread
// final reduction pairs bins (u, u+256) = first step of the old 512-tree,
// so the summation order (and result) is unchanged.
// ---------------------------------------------------------------------------
__device__ double br256(double v, double* buf) {
    int tid = threadIdx.x;
    buf[tid] = v;
    __syncthreads();
    for (int off = 128; off > 0; off >>= 1) {
        if (tid < off) buf[tid] += buf[tid + off];
        __syncthreads();
    }
    double r = buf[0];
    __syncthreads();
    return r;
}

__global__ __launch_bounds__(256)
void reduce_final_kernel(const float* __restrict__ parts,
                         const int* __restrict__ partsI,
                         float* __restrict__ accum,
                         int* __restrict__ accumI,
                         int* __restrict__ cnt,
                         float* __restrict__ out,
                         int B) {
    int s = blockIdx.x;              // 0..406
    int u = threadIdx.x;
    int npart = 4 * B;
    __shared__ float r4[4];
    __shared__ int   ri4[4];
    __shared__ int   lastFlag;

    if (s < PSTRIDE) {
        float acc = 0.f;
        for (int p = u; p < npart; p += 256) acc += parts[(size_t)p * PSTRIDE + s];
        #pragma unroll
        for (int off = 32; off > 0; off >>= 1) acc += __shfl_down(acc, off, 64);
        if ((u & 63) == 0) r4[u >> 6] = acc;
        __syncthreads();
        if (u == 0)
            __hip_atomic_store(&accum[s], r4[0] + r4[1] + r4[2] + r4[3],
                               __ATOMIC_RELAXED, __HIP_MEMORY_SCOPE_AGENT);
    } else {
        int col = s - PSTRIDE;       // 0: nc_sum, 1: same_cnt (exact ints)
        int acc = 0;
        for (int p = u; p < B; p += 256) acc += partsI[col * B + p];
        #pragma unroll
        for (int off = 32; off > 0; off >>= 1) acc += __shfl_down(acc, off, 64);
        if ((u & 63) == 0) ri4[u >> 6] = acc;
        __syncthreads();
        if (u == 0)
            __hip_atomic_store(&accumI[col], ri4[0] + ri4[1] + ri4[2] + ri4[3],
                               __ATOMIC_RELAXED, __HIP_MEMORY_SCOPE_AGENT);
    }

    if (u == 0) {
        int prev = __hip_atomic_fetch_add(cnt, 1, __ATOMIC_ACQ_REL,
                                          __HIP_MEMORY_SCOPE_AGENT);
        lastFlag = (prev == (int)gridDim.x - 1);
    }
    __syncthreads();
    if (!lastFlag) return;

    // ---- final (runs in whichever block finished last) ----
    __shared__ double dred[256];

    double nc_sum   = (double)__hip_atomic_load(&accumI[0], __ATOMIC_RELAXED,
                                                __HIP_MEMORY_SCOPE_AGENT);
    double same_cnt = (double)__hip_atomic_load(&accumI[1], __ATOMIC_RELAXED,
                                                __HIP_MEMORY_SCOPE_AGENT);
    double total_maskf = (double)B * ((double)LL - 3.0 * LBINS + 2.0);
    double diff_cnt = total_maskf - same_cnt;

    float w0 = 0.f, x0 = 0.f, y0 = 0.f;
    float w1 = 0.f, x1 = 0.f, y1 = 0.f;
    {
        int t0 = u;                  // always < LBINS
        float a0 = __hip_atomic_load(&accum[t0], __ATOMIC_RELAXED,
                                     __HIP_MEMORY_SCOPE_AGENT);
        float cntB = ((t0 == 0) ? (float)LBINS : 2.0f * (float)(LBINS - t0)) * (float)B;
        float mc = a0 / cntB;
        int valid = (t0 >= MIN_SEP) && __builtin_isfinite(mc) && (mc > 0.0f);
        w0 = valid ? 1.f : 0.f;
        x0 = logf(fmaxf((float)t0, 1.0f));
        y0 = logf((valid ? mc : 1.0f) + 1e-6f);
    }
    int t1 = u + 256;
    if (t1 < LBINS) {
        float a1 = __hip_atomic_load(&accum[t1], __ATOMIC_RELAXED,
                                     __HIP_MEMORY_SCOPE_AGENT);
        float cntB = 2.0f * (float)(LBINS - t1) * (float)B;
        float mc = a1 / cntB;
        int valid = __builtin_isfinite(mc) && (mc > 0.0f);   // t1 >= MIN_SEP always
        w1 = valid ? 1.f : 0.f;
        x1 = logf((float)t1);
        y1 = logf((valid ? mc : 1.0f) + 1e-6f);
    }
    double n  = br256((double)w0 + (double)w1, dred);
    double Sx = br256((double)(w0 * x0) + (double)(w1 * x1), dred);
    double Sy = br256((double)(w0 * y0) + (double)(w1 * y1), dred);
    double n_safe = fmax(n, 1.0);
    double xm = Sx / n_safe, ym = Sy / n_safe;
    double num = br256((double)w0 * ((double)x0 - xm) * ((double)y0 - ym)
                     + (double)w1 * ((double)x1 - xm) * ((double)y1 - ym), dred);
    double den = br256((double)w0 * ((double)x0 - xm) * ((double)x0 - xm)
                     + (double)w1 * ((double)x1 - xm) * ((double)x1 - xm), dred);

    if (u == 0) {
        double slope = num / (den + 1e-8);
        float dist_loss = (n >= 5.0) ? (float)((slope + 0.85) * (slope + 0.85)) : 0.0f;

        float fHA = __hip_atomic_load(&accum[ACC_HANY],  __ATOMIC_RELAXED, __HIP_MEMORY_SCOPE_AGENT);
        float fHC = __hip_atomic_load(&accum[ACC_HCONV], __ATOMIC_RELAXED, __HIP_MEMORY_SCOPE_AGENT);
        float fSW = __hip_atomic_load(&accum[ACC_SWM],   __ATOMIC_RELAXED, __HIP_MEMORY_SCOPE_AGENT);
        float fSM = __hip_atomic_load(&accum[ACC_SMM],   __ATOMIC_RELAXED, __HIP_MEMORY_SCOPE_AGENT);

        float ncf = (float)nc_sum;
        float hinge = (fHA - fHC) / (ncf + 1e-6f);
        float ctcf_loss = (ncf < 1.0f) ? 0.0f : hinge;

        float within  = fSW / (float)fmax(same_cnt, 1.0);
        float between = (fSM - fSW) / (float)fmax(diff_cnt, 1.0);
        float ratio = within / (fabsf(between) + 1e-6f);
        float comp_loss = fmaxf(1.5f - ratio, 0.0f);

        float total = 1.0f * dist_loss + 0.5f * ctcf_loss + 0.5f * comp_loss;
        out[0] = dist_loss;
        out[1] = ctcf_loss;
        out[2] = comp_loss;
        out[3] = total;
    }
}

// ---------------------------------------------------------------------------
extern "C" void kernel_launch(void* const* d_in, const int* in_sizes, int n_in,
                              void* d_out, int out_size, void* d_ws, size_t ws_size,
                              hipStream_t stream) {
    const float* cm     = (const float*)d_in[0];   // (B, L, L) fp32
    const float* logits = (const float*)d_in[1];   // (B, L, 2) fp32
    const int*   ctcf   = (const int*)d_in[2];     // (B, L) int32
    float* out = (float*)d_out;

    int total = in_sizes[0];
    int B = total / LL;

    float* wsf    = (float*)d_ws;
    float* accum  = wsf;                        // 405 floats
    int*   accumI = (int*)(wsf + 408);          // 2 ints (nc_sum, same_cnt)
    int*   cnt    = (int*)(wsf + 412);          // finish counter
    int*   partsI = (int*)(wsf + 416);          // 2*B ints (per-batch counts)
    int parts_off = (416 + 2 * B + 255) & ~255;
    float* parts  = wsf + parts_off;            // 4*B * PSTRIDE floats

    main_kernel<<<dim3(B, 4), 256, 0, stream>>>(cm, logits, ctcf, parts, partsI, cnt);
    reduce_final_kernel<<<PSTRIDE + 2, 256, 0, stream>>>(parts, partsI, accum,
                                                         accumI, cnt, out, B);
}